// Round 11
// baseline (624.201 us; speedup 1.0000x reference)
//
#include <hip/hip_runtime.h>
#include <math.h>

#define B 32768
#define S 256
#define H1 10
#define H2 6
#define ROWS 512                 // batch rows per wave
#define CH (B / ROWS)            // 64 chunks per subnet
#define WPB 4                    // waves per block (256 threads)
#define NBLK (S * CH / WPB)      // 4096 blocks
#define L2_SMOOTH 1e-3f
#define EPS 1e-10f

#define LSC 2.8853900817779268f  // 2*log2(e): prescale so exp2(a_s) = e^{2a}
#define C2L 0.6931471805599453f  // 2/LSC = ln 2
#define RLS 0.34657359027997264f // 1/LSC

typedef __attribute__((ext_vector_type(2))) float v2f;

__device__ __forceinline__ int rfl_i(int x) { return __builtin_amdgcn_readfirstlane(x); }
__device__ __forceinline__ float rfl(float x) {
    return __int_as_float(__builtin_amdgcn_readfirstlane(__float_as_int(x)));
}

// Batch-packed tanh + sech^2 from PRE-SCALED args (exp2(a_s) = e^{2a}).
// exp2/rcp are lane-scalar ops (done per half); surrounding algebra packs.
__device__ __forceinline__ void tanh_pair_v2(v2f a, v2f& th, v2f& s2) {
    v2f e, r;
    e.x = __builtin_amdgcn_exp2f(a.x);
    e.y = __builtin_amdgcn_exp2f(a.y);
    const v2f ep1 = e + 1.0f;
    r.x = __builtin_amdgcn_rcpf(ep1.x);
    r.y = __builtin_amdgcn_rcpf(ep1.y);
    th = r * (-2.0f) + 1.0f;          // tanh = 1 - 2r
    s2 = (r * 4.0f) * (1.0f - r);     // sech^2 = 4r(1-r)
}

// K1: wave = one subnet, lane = batch row, TWO rows per iter packed as v2f.
// Weights stay SCALAR floats (rfl -> SGPR; proven resident in R5 at VGPR=40).
// v2f state gives pk-math + ILP2 without weight registers. (256,4): cap 128,
// spill structurally impossible (R8/R10 failure mode: cap 40 < ~60 demand).
__global__ __launch_bounds__(256, 4) void k1_mlp(
    const float* __restrict__ x,
    const float* __restrict__ W1, const float* __restrict__ b1,
    const float* __restrict__ W2, const float* __restrict__ b2,
    const float* __restrict__ W3, const float* __restrict__ b3,
    float* __restrict__ out,          // [B][S] unnormalized (d_out)
    float* __restrict__ psum,         // [S][CH]
    float* __restrict__ psum2,        // [S][CH]
    float* __restrict__ pg2)          // [S][CH]
{
    const int t   = threadIdx.x;
    const int wid = (int)blockIdx.x * WPB + rfl_i(t >> 6);
    const int l   = t & 63;
    const int s   = wid & (S - 1);    // subnet (adjacent waves -> adjacent subnets)
    const int c   = wid >> 8;         // batch chunk 0..CH-1

    // ---- wave-uniform scalar parameters (SGPR); scaling folded once ----
    float w1[H1], w1e[H1], b1e[H1], m2w1[H1];
#pragma unroll
    for (int i = 0; i < H1; ++i) {
        const float w = rfl(W1[s * H1 + i]);
        w1[i]   = w;
        w1e[i]  = w * LSC;
        m2w1[i] = -2.0f * w * w;
        b1e[i]  = rfl(b1[s * H1 + i]) * LSC;
    }
    float w2s[H1][H2];
#pragma unroll
    for (int i = 0; i < H1; ++i)
#pragma unroll
        for (int j = 0; j < H2; ++j)
            w2s[i][j] = rfl(W2[(s * H1 + i) * H2 + j]) * LSC;
    float b2s[H2], w3s[H2], w3g[H2];
#pragma unroll
    for (int j = 0; j < H2; ++j) {
        b2s[j] = rfl(b2[s * H2 + j]) * LSC;
        const float w = rfl(W3[s * H2 + j]);
        w3s[j] = w;
        w3g[j] = w * RLS;             // w3/L for the g2 accumulation
    }
    const float bb3 = rfl(b3[s]);

    const size_t base = (size_t)(c * ROWS + l) * S + s;
    const float* px = x   + base;
    float*       po = out + base;

    float so = 0.0f, so2 = 0.0f, sg2 = 0.0f;

#pragma unroll 1
    for (int k = 0; k < ROWS / 128; ++k) {      // rows k*128+l and k*128+64+l
        v2f x2;
        x2.x = px[(size_t)(k * 128)      * S];
        x2.y = px[(size_t)(k * 128 + 64) * S];

        v2f v[H2], vp[H2], vpp[H2];
        {   // i = 0 peeled: init from b2s (scalar broadcast)
            v2f h2, t2;
            tanh_pair_v2(x2 * w1e[0] + b1e[0], h2, t2);
            const v2f hp2  = t2 * w1[0];
            const v2f hpp2 = (h2 * hp2) * m2w1[0];
#pragma unroll
            for (int j = 0; j < H2; ++j) {
                v[j]   = h2   * w2s[0][j] + b2s[j];
                vp[j]  = hp2  * w2s[0][j];
                vpp[j] = hpp2 * w2s[0][j];
            }
        }
#pragma unroll
        for (int i = 1; i < H1; ++i) {
            v2f h2, t2;
            tanh_pair_v2(x2 * w1e[i] + b1e[i], h2, t2);
            const v2f hp2  = t2 * w1[i];
            const v2f hpp2 = (h2 * hp2) * m2w1[i];
#pragma unroll
            for (int j = 0; j < H2; ++j) {
                v[j]   = h2   * w2s[i][j] + v[j];     // pk-fma, scalar weight
                vp[j]  = hp2  * w2s[i][j] + vp[j];
                vpp[j] = hpp2 * w2s[i][j] + vpp[j];
            }
        }

        v2f o2, q2;
        {   // j = 0 peeled
            v2f g2v, tg2;
            tanh_pair_v2(v[0], g2v, tg2);
            const v2f cc  = (g2v * vp[0]) * (-C2L);
            const v2f gpp = tg2 * (cc * vp[0] + vpp[0]);
            o2 = g2v * w3s[0] + bb3;
            q2 = gpp * w3g[0];
        }
#pragma unroll
        for (int j = 1; j < H2; ++j) {
            v2f g2v, tg2;
            tanh_pair_v2(v[j], g2v, tg2);
            const v2f cc  = (g2v * vp[j]) * (-C2L);
            const v2f gpp = tg2 * (cc * vp[j] + vpp[j]);
            o2 = g2v * w3s[j] + o2;
            q2 = gpp * w3g[j] + q2;
        }

        po[(size_t)(k * 128)      * S] = o2.x;
        po[(size_t)(k * 128 + 64) * S] = o2.y;
        so  += o2.x + o2.y;
        so2  = fmaf(o2.x, o2.x, fmaf(o2.y, o2.y, so2));
        sg2  = fmaf(q2.x, q2.x, fmaf(q2.y, q2.y, sg2));
    }

    // deterministic in-wave butterfly reduction
#pragma unroll
    for (int m = 1; m < 64; m <<= 1) {
        so  += __shfl_xor(so,  m, 64);
        so2 += __shfl_xor(so2, m, 64);
        sg2 += __shfl_xor(sg2, m, 64);
    }
    if (l == 0) {
        psum [s * CH + c] = so;
        psum2[s * CH + c] = so2;
        pg2  [s * CH + c] = sg2;
    }
}

// K2: one wave per subnet reduces CH=64 partials -> mean, 1/std, smooth term
__global__ __launch_bounds__(64) void k2_reduce(
    const float* __restrict__ psum, const float* __restrict__ psum2,
    const float* __restrict__ pg2,
    float* __restrict__ mean_arr, float* __restrict__ rstd_arr,
    float* __restrict__ smooth_arr)
{
    const int s = blockIdx.x;
    const int l = threadIdx.x;       // 0..63 == CH

    float a  = psum [s * CH + l];
    float b_ = psum2[s * CH + l];
    float cc = pg2  [s * CH + l];
#pragma unroll
    for (int m = 1; m < 64; m <<= 1) {
        a  += __shfl_xor(a,  m, 64);
        b_ += __shfl_xor(b_, m, 64);
        cc += __shfl_xor(cc, m, 64);
    }
    if (l == 0) {
        const float inv_b = 1.0f / (float)B;
        const float mean  = a * inv_b;
        float var = b_ * inv_b - mean * mean;
        var = fmaxf(var, 0.0f);
        const float stdv = fmaxf(sqrtf(var), EPS);
        const float rstd = 1.0f / stdv;
        mean_arr[s]   = mean;
        rstd_arr[s]   = rstd;
        smooth_arr[s] = (cc * inv_b) * rstd;   // mean(g2^2)/std
    }
}

// K3: normalize d_out in place (float4), plus one block for the loss sum
#define K3_NORM_BLOCKS (B * S / (256 * 4))   // 8192
__global__ __launch_bounds__(256) void k3_norm(
    float* __restrict__ out,
    const float* __restrict__ mean_arr, const float* __restrict__ rstd_arr,
    const float* __restrict__ smooth_arr)
{
    if ((int)blockIdx.x == K3_NORM_BLOCKS) {
        const int t = threadIdx.x;
        __shared__ float sa[256];
        sa[t] = smooth_arr[t];
        __syncthreads();
        for (int st = 128; st > 0; st >>= 1) {
            if (t < st) sa[t] += sa[t + st];
            __syncthreads();
        }
        if (t == 0) out[B * S] = L2_SMOOTH * sa[0];
        return;
    }

    const int i4   = (int)blockIdx.x * 256 + (int)threadIdx.x;
    const int base = i4 * 4;
    float4 v = *reinterpret_cast<float4*>(&out[base]);
    const int s0 = base & (S - 1);
    v.x = (v.x - mean_arr[s0 + 0]) * rstd_arr[s0 + 0];
    v.y = (v.y - mean_arr[s0 + 1]) * rstd_arr[s0 + 1];
    v.z = (v.z - mean_arr[s0 + 2]) * rstd_arr[s0 + 2];
    v.w = (v.w - mean_arr[s0 + 3]) * rstd_arr[s0 + 3];
    *reinterpret_cast<float4*>(&out[base]) = v;
}

extern "C" void kernel_launch(void* const* d_in, const int* in_sizes, int n_in,
                              void* d_out, int out_size, void* d_ws, size_t ws_size,
                              hipStream_t stream) {
    const float* x  = (const float*)d_in[0];
    const float* W1 = (const float*)d_in[1];
    const float* b1 = (const float*)d_in[2];
    const float* W2 = (const float*)d_in[3];
    const float* b2 = (const float*)d_in[4];
    const float* W3 = (const float*)d_in[5];
    const float* b3 = (const float*)d_in[6];
    float* out = (float*)d_out;

    // ws (floats): psum[S*CH] | psum2[S*CH] | pg2[S*CH] | mean[S] | rstd[S] | smooth[S]
    float* psum   = (float*)d_ws;
    float* psum2  = psum  + S * CH;
    float* pg2    = psum2 + S * CH;
    float* meanA  = pg2   + S * CH;
    float* rstdA  = meanA + S;
    float* smooth = rstdA + S;

    k1_mlp<<<NBLK, 64 * WPB, 0, stream>>>(
        x, W1, b1, W2, b2, W3, b3, out, psum, psum2, pg2);
    k2_reduce<<<S, 64, 0, stream>>>(psum, psum2, pg2, meanA, rstdA, smooth);
    k3_norm<<<K3_NORM_BLOCKS + 1, 256, 0, stream>>>(out, meanA, rstdA, smooth);
}

// Round 13
// 116.625 us; speedup vs baseline: 5.3522x; 5.3522x over previous
//
#include <hip/hip_runtime.h>
#include <math.h>

#define B 32768
#define S 256
#define H1 10
#define H2 6
#define ROWS 512                 // batch rows per wave
#define CH (B / ROWS)            // 64 chunks per subnet
#define WPB 4                    // waves per block (256 threads)
#define NBLK (S * CH / WPB)      // 4096 blocks
#define L2_SMOOTH 1e-3f
#define EPS 1e-10f

__device__ __forceinline__ int rfl_i(int x) { return __builtin_amdgcn_readfirstlane(x); }
__device__ __forceinline__ float rfl(float x) {
    return __int_as_float(__builtin_amdgcn_readfirstlane(__float_as_int(x)));
}

// tanh + sech^2 via Pade(7,6) continued-fraction rational, clamp |x|<=5.
//   tanh(x) ~ x(135135 + 17325x^2 + 378x^4 + x^6) /
//              (135135 + 62370x^2 + 3150x^4 + 28x^6)
// abs err <= ~1e-4 on [-5,5]; clamping adds <= 9.1e-5 beyond. ONE trans op
// (v_rcp) instead of two (v_exp + v_rcp) — tests the trans-issue-cost theory.
__device__ __forceinline__ void tanh_pair_p(float x, float& th, float& s2) {
    x = fminf(fmaxf(x, -5.0f), 5.0f);
    const float x2 = x * x;
    float n = x2 + 378.0f;
    n = fmaf(n, x2, 17325.0f);
    n = fmaf(n, x2, 135135.0f);
    n = n * x;
    float d = fmaf(x2, 28.0f, 3150.0f);
    d = fmaf(d, x2, 62370.0f);
    d = fmaf(d, x2, 135135.0f);
    th = n * __builtin_amdgcn_rcpf(d);
    s2 = fmaf(-th, th, 1.0f);        // sech^2 = 1 - tanh^2
}

// K1: wave = one subnet, lane = batch row. Weights wave-uniform (SGPR, scalar
// consumers only — pk/VOP3P forms demote weights to scratch, R6-R11). No LDS.
__global__ __launch_bounds__(256, 6) void k1_mlp(
    const float* __restrict__ x,
    const float* __restrict__ W1, const float* __restrict__ b1,
    const float* __restrict__ W2, const float* __restrict__ b2,
    const float* __restrict__ W3, const float* __restrict__ b3,
    float* __restrict__ out,          // [B][S] unnormalized (d_out)
    float* __restrict__ psum,         // [S][CH]
    float* __restrict__ psum2,        // [S][CH]
    float* __restrict__ pg2)          // [S][CH]
{
    const int t   = threadIdx.x;
    const int wid = (int)blockIdx.x * WPB + rfl_i(t >> 6);
    const int l   = t & 63;
    const int s   = wid & (S - 1);    // subnet (adjacent waves -> adjacent subnets)
    const int c   = wid >> 8;         // batch chunk 0..CH-1

    // ---- wave-uniform scalar parameters (SGPR via readfirstlane) ----
    float w1[H1], bb1[H1], m2w1[H1];
#pragma unroll
    for (int i = 0; i < H1; ++i) {
        const float w = rfl(W1[s * H1 + i]);
        w1[i]   = w;
        m2w1[i] = -2.0f * w;          // hpp = (h*hp)*(-2*w1)
        bb1[i]  = rfl(b1[s * H1 + i]);
    }
    float w2s[H1][H2];
#pragma unroll
    for (int i = 0; i < H1; ++i)
#pragma unroll
        for (int j = 0; j < H2; ++j)
            w2s[i][j] = rfl(W2[(s * H1 + i) * H2 + j]);
    float b2s[H2], w3s[H2];
#pragma unroll
    for (int j = 0; j < H2; ++j) {
        b2s[j] = rfl(b2[s * H2 + j]);
        w3s[j] = rfl(W3[s * H2 + j]);
    }
    const float bb3 = rfl(b3[s]);

    const size_t base = (size_t)(c * ROWS + l) * S + s;
    const float* px = x   + base;
    float*       po = out + base;

    float so = 0.0f, so2 = 0.0f, sg2 = 0.0f;

#pragma unroll 1
    for (int k = 0; k < ROWS / 64; ++k) {
        const float xs = px[(size_t)(k * 64) * S];

        float v[H2], vp[H2], vpp[H2];
        {   // i = 0 peeled: initializes v/vp/vpp without v_mov chains
            float h, tt;
            tanh_pair_p(fmaf(xs, w1[0], bb1[0]), h, tt);
            const float hp  = tt * w1[0];
            const float hpp = (h * hp) * m2w1[0];
#pragma unroll
            for (int j = 0; j < H2; ++j) {
                v[j]   = fmaf(h, w2s[0][j], b2s[j]);
                vp[j]  = hp  * w2s[0][j];
                vpp[j] = hpp * w2s[0][j];
            }
        }
#pragma unroll
        for (int i = 1; i < H1; ++i) {
            float h, tt;
            tanh_pair_p(fmaf(xs, w1[i], bb1[i]), h, tt);
            const float hp  = tt * w1[i];
            const float hpp = (h * hp) * m2w1[i];
#pragma unroll
            for (int j = 0; j < H2; ++j) {
                v[j]   = fmaf(h,   w2s[i][j], v[j]);
                vp[j]  = fmaf(hp,  w2s[i][j], vp[j]);
                vpp[j] = fmaf(hpp, w2s[i][j], vpp[j]);
            }
        }

        float o, g2;
        {   // j = 0 peeled
            float g, tg;
            tanh_pair_p(v[0], g, tg);
            const float c0  = -2.0f * (g * vp[0]);
            const float gpp = tg * fmaf(c0, vp[0], vpp[0]);
            o  = fmaf(g, w3s[0], bb3);
            g2 = gpp * w3s[0];
        }
#pragma unroll
        for (int j = 1; j < H2; ++j) {
            float g, tg;
            tanh_pair_p(v[j], g, tg);
            const float cj  = -2.0f * (g * vp[j]);
            const float gpp = tg * fmaf(cj, vp[j], vpp[j]);
            o  = fmaf(g,     w3s[j], o);
            g2 = fmaf(w3s[j], gpp,   g2);
        }

        po[(size_t)(k * 64) * S] = o;
        so += o; so2 = fmaf(o, o, so2); sg2 = fmaf(g2, g2, sg2);
    }

    // deterministic in-wave butterfly reduction
#pragma unroll
    for (int m = 1; m < 64; m <<= 1) {
        so  += __shfl_xor(so,  m, 64);
        so2 += __shfl_xor(so2, m, 64);
        sg2 += __shfl_xor(sg2, m, 64);
    }
    if (l == 0) {
        psum [s * CH + c] = so;
        psum2[s * CH + c] = so2;
        pg2  [s * CH + c] = sg2;
    }
}

// K2: one wave per subnet reduces CH=64 partials -> mean, 1/std, smooth term
__global__ __launch_bounds__(64) void k2_reduce(
    const float* __restrict__ psum, const float* __restrict__ psum2,
    const float* __restrict__ pg2,
    float* __restrict__ mean_arr, float* __restrict__ rstd_arr,
    float* __restrict__ smooth_arr)
{
    const int s = blockIdx.x;
    const int l = threadIdx.x;       // 0..63 == CH

    float a  = psum [s * CH + l];
    float b_ = psum2[s * CH + l];
    float cc = pg2  [s * CH + l];
#pragma unroll
    for (int m = 1; m < 64; m <<= 1) {
        a  += __shfl_xor(a,  m, 64);
        b_ += __shfl_xor(b_, m, 64);
        cc += __shfl_xor(cc, m, 64);
    }
    if (l == 0) {
        const float inv_b = 1.0f / (float)B;
        const float mean  = a * inv_b;
        float var = b_ * inv_b - mean * mean;
        var = fmaxf(var, 0.0f);
        const float stdv = fmaxf(sqrtf(var), EPS);
        const float rstd = 1.0f / stdv;
        mean_arr[s]   = mean;
        rstd_arr[s]   = rstd;
        smooth_arr[s] = (cc * inv_b) * rstd;   // mean(g2^2)/std
    }
}

// K3: normalize d_out in place (float4), plus one block for the loss sum
#define K3_NORM_BLOCKS (B * S / (256 * 4))   // 8192
__global__ __launch_bounds__(256) void k3_norm(
    float* __restrict__ out,
    const float* __restrict__ mean_arr, const float* __restrict__ rstd_arr,
    const float* __restrict__ smooth_arr)
{
    if ((int)blockIdx.x == K3_NORM_BLOCKS) {
        const int t = threadIdx.x;
        __shared__ float sa[256];
        sa[t] = smooth_arr[t];
        __syncthreads();
        for (int st = 128; st > 0; st >>= 1) {
            if (t < st) sa[t] += sa[t + st];
            __syncthreads();
        }
        if (t == 0) out[B * S] = L2_SMOOTH * sa[0];
        return;
    }

    const int i4   = (int)blockIdx.x * 256 + (int)threadIdx.x;
    const int base = i4 * 4;
    float4 v = *reinterpret_cast<float4*>(&out[base]);
    const int s0 = base & (S - 1);
    v.x = (v.x - mean_arr[s0 + 0]) * rstd_arr[s0 + 0];
    v.y = (v.y - mean_arr[s0 + 1]) * rstd_arr[s0 + 1];
    v.z = (v.z - mean_arr[s0 + 2]) * rstd_arr[s0 + 2];
    v.w = (v.w - mean_arr[s0 + 3]) * rstd_arr[s0 + 3];
    *reinterpret_cast<float4*>(&out[base]) = v;
}

extern "C" void kernel_launch(void* const* d_in, const int* in_sizes, int n_in,
                              void* d_out, int out_size, void* d_ws, size_t ws_size,
                              hipStream_t stream) {
    const float* x  = (const float*)d_in[0];
    const float* W1 = (const float*)d_in[1];
    const float* b1 = (const float*)d_in[2];
    const float* W2 = (const float*)d_in[3];
    const float* b2 = (const float*)d_in[4];
    const float* W3 = (const float*)d_in[5];
    const float* b3 = (const float*)d_in[6];
    float* out = (float*)d_out;

    // ws (floats): psum[S*CH] | psum2[S*CH] | pg2[S*CH] | mean[S] | rstd[S] | smooth[S]
    float* psum   = (float*)d_ws;
    float* psum2  = psum  + S * CH;
    float* pg2    = psum2 + S * CH;
    float* meanA  = pg2   + S * CH;
    float* rstdA  = meanA + S;
    float* smooth = rstdA + S;

    k1_mlp<<<NBLK, 64 * WPB, 0, stream>>>(
        x, W1, b1, W2, b2, W3, b3, out, psum, psum2, pg2);
    k2_reduce<<<S, 64, 0, stream>>>(psum, psum2, pg2, meanA, rstdA, smooth);
    k3_norm<<<K3_NORM_BLOCKS + 1, 256, 0, stream>>>(out, meanA, rstdA, smooth);
}